// Round 12
// baseline (321.224 us; speedup 1.0000x reference)
//
#include <hip/hip_runtime.h>
#include <hip/hip_bf16.h>

#define NN 50000
#define NE 800000
#define D_NODE 64
#define D_MSG 96      // 64 + 16 + 16
#define D_K 160       // compute K: 64 (x) + 96 (0.5*agg)
#define AS 192        // A row stride in bf16 (384 B, 128B-aligned rows)
#define D_OUT 128
#define KP 168        // padded K stride for Bt (336B rows, 16B-aligned)

#define SCAN_BLOCKS 49     // ceil(12500 int4 groups / 256)
#define XCAST_BLOCKS 3125  // NN*16/256
#define BT_BLOCKS 80       // 20480 Bt elements / 256

typedef __attribute__((ext_vector_type(8))) short bf16x8;
typedef __attribute__((ext_vector_type(4))) float f32x4;

// ---------------- ws layout (all ranges disjoint / ordering-safe) ----------
// cnt : [0,       200000)
// done: [200000,  200064)   scan phase-A counter   (own 64B line)
// done2:[200064,  200128)   scan-complete counter  (own 64B line)
// tick: [200128,  200192)   scan ticket            (own 64B line)
// off : [200192,  400192)
// cur : [400192,  600192)   cur DEAD after bucket; Bt (43008B) rides here
// perm: [600192,  7000192)  NE * 8  (16B aligned)
// A   : [7000192, 26200192) NN * 192 * 2  (7000192 % 128 == 0)
//   A row: [x bf16 (0-63) | 0.5*msg_x (64-127) | 0.5*msg_e (128-159) | pad]
// bsum: A_OFF+128 (A row 0 cols 64..161): written by scan AFTER prep/xcast
//   (xcast touches cols 0-63 only), read before gather overwrites cols 64+.
#define CNT_OFF   0
#define DONE_OFF  200000
#define DONE2_OFF 200064
#define TICK_OFF  200128
#define OFF_OFF   200192
#define CUR_OFF   400192
#define PERM_OFF  600192
#define A_OFF     7000192
#define BSUM_OFF  (A_OFF + 128)

__device__ __forceinline__ unsigned short f2bf(float f) {
    __hip_bfloat16 h = __float2bfloat16(f);   // RNE
    union { __hip_bfloat16 h; unsigned short u; } c; c.h = h;
    return c.u;
}
__device__ __forceinline__ float bf2f(unsigned int u) {
    union { unsigned int i; float f; } c; c.i = u << 16; return c.f;
}

// ---------------------------------------------------------------------------
// Step 1 (fused): blocks [0,3125): cast x -> A cols 0..63 (bf16, aligned);
//                 blocks [3125,6250): per-row histogram.
// ---------------------------------------------------------------------------
__global__ __launch_bounds__(256) void prep_kernel(
    const float* __restrict__ x, unsigned short* __restrict__ A,
    const int* __restrict__ row, int* __restrict__ cnt)
{
    const int b = blockIdx.x;
    if (b < XCAST_BLOCKS) {
        int i = b * 256 + threadIdx.x;        // < NN*16 exactly
        int node = i >> 4, c4 = i & 15;
        float4 v = *(const float4*)(x + (size_t)node * D_NODE + c4 * 4);
        uint2 pk;
        pk.x = (unsigned)f2bf(v.x) | ((unsigned)f2bf(v.y) << 16);
        pk.y = (unsigned)f2bf(v.z) | ((unsigned)f2bf(v.w) << 16);
        *(uint2*)(A + (size_t)node * AS + c4 * 4) = pk;
    } else {
        int e = (b - XCAST_BLOCKS) * 256 + threadIdx.x;
        if (e < NE) atomicAdd(&cnt[row[e]], 1);
    }
}

// ---------------------------------------------------------------------------
// Step 2+3 fused: scan (by the first 49 ARRIVING blocks, ticket-based — no
// dispatch-order assumption) + bucket (all 3125 blocks, 1 edge/thread).
// Each block prefetches its edge's (row,col) before waiting, so bucket's
// 6.4 MB read overlaps the scan.
// ---------------------------------------------------------------------------
__global__ __launch_bounds__(256) void scanbucket_kernel(
    const int* __restrict__ row, const int* __restrict__ col,
    const int* __restrict__ cnt, int* __restrict__ bsum,
    int* __restrict__ off, int* __restrict__ cur,
    int* __restrict__ done, int* __restrict__ done2, int* __restrict__ tick,
    int2* __restrict__ perm)
{
    const int t = threadIdx.x;
    const int e = blockIdx.x * 256 + t;        // NE == 3125*256, always valid
    const int er = row[e];                      // prefetch: in flight during scan
    const int ec = col[e];

    __shared__ int s_tk;
    if (t == 0) s_tk = atomicAdd(tick, 1);
    __syncthreads();
    const int tk = s_tk;

    if (tk < SCAN_BLOCKS) {
        // ---- scan chunk #tk (r10-proven structure, b -> tk) ----
        const int idx4 = tk * 256 + t;
        const bool valid = (idx4 < NN / 4);

        __shared__ int wsumA[4];
        int4 c = make_int4(0, 0, 0, 0);
        if (valid) c = ((const int4*)cnt)[idx4];
        int s = c.x + c.y + c.z + c.w;
        {
            int r = s;
            for (int d = 32; d > 0; d >>= 1) r += __shfl_down(r, d);
            if ((t & 63) == 0) wsumA[t >> 6] = r;
        }
        __syncthreads();
        if (t == 0) {
            bsum[tk] = wsumA[0] + wsumA[1] + wsumA[2] + wsumA[3];
            __threadfence();                   // release bsum[tk]
            atomicAdd(done, 1);
            while (__hip_atomic_load(done, __ATOMIC_ACQUIRE,
                                     __HIP_MEMORY_SCOPE_AGENT) < SCAN_BLOCKS)
                __builtin_amdgcn_s_sleep(1);
        }
        __syncthreads();                       // all threads see bsum complete

        __shared__ int s_boff;
        __shared__ int wsumC[4];
        if (t < 64) {                          // wave 0: scan the 49 block sums
            int v = (t < SCAN_BLOCKS) ? bsum[t] : 0;
            int orig = v;
            for (int d = 1; d < 64; d <<= 1) {
                int u = __shfl_up(v, d);
                if (t >= d) v += u;
            }
            int excl = v - orig;
            int want = __shfl(excl, tk);
            if (t == 0) s_boff = want;
        }

        const int lane = t & 63, w = t >> 6;
        int v = s;
        for (int d = 1; d < 64; d <<= 1) {
            int u = __shfl_up(v, d);
            if (lane >= d) v += u;
        }
        if (lane == 63) wsumC[w] = v;
        __syncthreads();
        int woff = 0;
        for (int i = 0; i < 4; ++i) if (i < w) woff += wsumC[i];

        if (valid) {
            int excl = (v - s) + woff + s_boff;
            int4 o;
            o.x = excl;
            o.y = o.x + c.x;
            o.z = o.y + c.y;
            o.w = o.z + c.z;
            ((int4*)off)[idx4] = o;
            ((int4*)cur)[idx4] = o;
        }
        __syncthreads();                       // block's off/cur stores done
        if (t == 0) {
            __threadfence();                   // publish off/cur device-wide
            atomicAdd(done2, 1);
        }
    }

    // ---- all blocks: wait until the whole scan is published ----
    if (t == 0) {
        while (__hip_atomic_load(done2, __ATOMIC_ACQUIRE,
                                 __HIP_MEMORY_SCOPE_AGENT) < SCAN_BLOCKS)
            __builtin_amdgcn_s_sleep(1);
    }
    __syncthreads();

    // ---- bucket ----
    int pos = atomicAdd(&cur[er], 1);
    perm[pos] = make_int2(e, ec);
}

// ---------------------------------------------------------------------------
// Step 4: gather-aggregate (blocks [0, NN/4)), 2 edges per wave-pass,
// 8-edge main unroll. Extra blocks convert B = [Wr ; Wm] -> bf16 Bt.
// ---------------------------------------------------------------------------
__global__ __launch_bounds__(256) void gather_kernel(
    const float* __restrict__ ea,   // NE x 16
    const float* __restrict__ et,   // NE x 16
    const int*  __restrict__ off,
    const int*  __restrict__ cnt,
    const int2* __restrict__ perm,
    unsigned short* __restrict__ A,
    const float* __restrict__ Wm,   // 96 x 128
    const float* __restrict__ Wr,   // 64 x 128
    unsigned short* __restrict__ Bt)
{
    const int grp = blockIdx.x;
    if (grp >= NN / 4) {
        int idx = (grp - NN / 4) * 256 + threadIdx.x;   // [0, 20480)
        int n = idx & 127, k = idx >> 7;
        float v = (k < D_NODE) ? Wr[k * D_OUT + n] : Wm[(k - D_NODE) * D_OUT + n];
        Bt[n * KP + k] = f2bf(v);
        return;
    }

    const int node = grp * 4 + (threadIdx.x >> 6);   // NN % 4 == 0
    const int lane = threadIdx.x & 63;

    const int beg = off[node];
    const int end = beg + cnt[node];

    const int half = lane >> 5;          // 0: even edge of pair, 1: odd
    const int hl   = lane & 31;
    const float* ebase = ((lane >> 4) & 1) ? et : ea;
    const int ecol = lane & 15;

    float accx0 = 0.f, accx1 = 0.f, acce = 0.f;
    float accx0b = 0.f, accx1b = 0.f, acceb = 0.f;

#define EDGE_PAIR(q, ax0, ax1, ae)                                          \
    {                                                                       \
        int cc = half ? (q).w : (q).y;                                      \
        int ee = half ? (q).z : (q).x;                                      \
        unsigned xv = *(const unsigned*)(A + (size_t)cc * AS + hl * 2);     \
        float ev = ebase[(size_t)ee * 16 + ecol];                           \
        ax0 += bf2f(xv & 0xffffu);                                          \
        ax1 += bf2f(xv >> 16);                                              \
        ae  += ev;                                                          \
    }

    int j = beg;
    if ((j & 1) && j < end) {            // peel to even index
        int2 p = perm[j];
        if (half == 0) {
            unsigned xv = *(const unsigned*)(A + (size_t)p.y * AS + hl * 2);
            accx0 += bf2f(xv & 0xffffu);
            accx1 += bf2f(xv >> 16);
            acce  += ebase[(size_t)p.x * 16 + ecol];
        }
        ++j;
    }
    for (; j + 8 <= end; j += 8) {       // 4 pairs per iter
        int4 q0 = *(const int4*)(perm + j);
        int4 q1 = *(const int4*)(perm + j + 2);
        int4 q2 = *(const int4*)(perm + j + 4);
        int4 q3 = *(const int4*)(perm + j + 6);
        EDGE_PAIR(q0, accx0, accx1, acce)
        EDGE_PAIR(q1, accx0b, accx1b, acceb)
        EDGE_PAIR(q2, accx0, accx1, acce)
        EDGE_PAIR(q3, accx0b, accx1b, acceb)
    }
    if (j + 4 <= end) {
        int4 q0 = *(const int4*)(perm + j);
        int4 q1 = *(const int4*)(perm + j + 2);
        EDGE_PAIR(q0, accx0, accx1, acce)
        EDGE_PAIR(q1, accx0b, accx1b, acceb)
        j += 4;
    }
    if (j + 2 <= end) {
        int4 q0 = *(const int4*)(perm + j);
        EDGE_PAIR(q0, accx0, accx1, acce)
        j += 2;
    }
    if (j < end) {
        int2 p = perm[j];
        if (half == 0) {
            unsigned xv = *(const unsigned*)(A + (size_t)p.y * AS + hl * 2);
            accx0 += bf2f(xv & 0xffffu);
            accx1 += bf2f(xv >> 16);
            acce  += ebase[(size_t)p.x * 16 + ecol];
        }
    }
#undef EDGE_PAIR

    accx0 += accx0b; accx1 += accx1b; acce += acceb;
    accx0 += __shfl_xor(accx0, 32);
    accx1 += __shfl_xor(accx1, 32);
    acce  += __shfl_xor(acce, 32);

    unsigned short* dst = A + (size_t)node * AS;
    if (half == 0) {
        unsigned pk = (unsigned)f2bf(0.5f * accx0)
                    | ((unsigned)f2bf(0.5f * accx1) << 16);
        *(unsigned*)(dst + D_NODE + hl * 2) = pk;       // cols 64..127
    } else {
        dst[2 * D_NODE + hl] = f2bf(0.5f * acce);       // cols 128..159
    }
}

// ---------------------------------------------------------------------------
// Step 5: MFMA GEMM  out[50000,128] = A[:, 0:160] @ Bt^T + bias.
// No LDS, no barrier; B-fragments from L2-resident pre-converted Bt.
// ---------------------------------------------------------------------------
__global__ __launch_bounds__(256) void mfma_dense_kernel(
    const unsigned short* __restrict__ A,   // NN x AS bf16
    const unsigned short* __restrict__ Bt,  // 128 x KP bf16
    const float* __restrict__ bm,           // 128
    const float* __restrict__ br,           // 128
    float*       __restrict__ out)          // NN x 128
{
    const int l   = threadIdx.x & 63;
    const int wid = threadIdx.x >> 6;
    const int wm  = wid & 1;                   // M half (32 rows)
    const int wn  = wid >> 1;                  // N half (64 cols)
    const int lr  = l & 15;
    const int lk  = (l >> 4) << 3;             // k sub-offset 0/8/16/24

    bf16x8 bq[4][5];
#pragma unroll
    for (int nf = 0; nf < 4; ++nf) {
        int c = wn * 64 + nf * 16 + lr;
#pragma unroll
        for (int ks = 0; ks < 5; ++ks)
            bq[nf][ks] = *(const bf16x8*)(Bt + c * KP + ks * 32 + lk);
    }

    const int row0 = blockIdx.x * 64 + wm * 32;

    f32x4 acc[2][4];
#pragma unroll
    for (int mf = 0; mf < 2; ++mf)
#pragma unroll
        for (int nf = 0; nf < 4; ++nf)
            acc[mf][nf] = (f32x4){0.f, 0.f, 0.f, 0.f};

#pragma unroll
    for (int ks = 0; ks < 5; ++ks) {
#pragma unroll
        for (int mf = 0; mf < 2; ++mf) {
            int row = row0 + mf * 16 + lr;
            if (row > NN - 1) row = NN - 1;    // clamp (dup rows never stored)
            bf16x8 af = *(const bf16x8*)(A + (size_t)row * AS + ks * 32 + lk);
#pragma unroll
            for (int nf = 0; nf < 4; ++nf)
                acc[mf][nf] = __builtin_amdgcn_mfma_f32_16x16x32_bf16(
                    af, bq[nf][ks], acc[mf][nf], 0, 0, 0);
        }
    }

#pragma unroll
    for (int nf = 0; nf < 4; ++nf) {
        int c = wn * 64 + nf * 16 + lr;
        float bias = 0.5f * bm[c] + br[c];
#pragma unroll
        for (int mf = 0; mf < 2; ++mf) {
            int rbase = row0 + mf * 16 + ((l >> 4) << 2);
#pragma unroll
            for (int r = 0; r < 4; ++r) {
                int row = rbase + r;
                if (row < NN) out[(size_t)row * D_OUT + c] = acc[mf][nf][r] + bias;
            }
        }
    }
}

extern "C" void kernel_launch(void* const* d_in, const int* in_sizes, int n_in,
                              void* d_out, int out_size, void* d_ws, size_t ws_size,
                              hipStream_t stream) {
    const float* x  = (const float*)d_in[0];
    const int*   ei = (const int*)d_in[1];   // row = ei[0:NE), col = ei[NE:2NE)
    const float* ea = (const float*)d_in[2];
    const float* et = (const float*)d_in[3];
    const float* Wm = (const float*)d_in[4];
    const float* bm = (const float*)d_in[5];
    const float* Wr = (const float*)d_in[6];
    const float* br = (const float*)d_in[7];
    float* out = (float*)d_out;
    const int* row = ei;
    const int* col = ei + NE;

    char* ws = (char*)d_ws;
    int*  cnt   = (int*)(ws + CNT_OFF);
    int*  done  = (int*)(ws + DONE_OFF);
    int*  done2 = (int*)(ws + DONE2_OFF);
    int*  tick  = (int*)(ws + TICK_OFF);
    int*  off   = (int*)(ws + OFF_OFF);
    int*  cur   = (int*)(ws + CUR_OFF);
    int2* perm  = (int2*)(ws + PERM_OFF);
    int*  bsum  = (int*)(ws + BSUM_OFF);     // inside A row 0 (see layout note)
    unsigned short* A  = (unsigned short*)(ws + A_OFF);
    unsigned short* Bt = (unsigned short*)(ws + CUR_OFF);  // cur dead post-bucket

    hipMemsetAsync(ws, 0, OFF_OFF, stream);  // zero cnt + done + done2 + tick
    prep_kernel      <<<2 * XCAST_BLOCKS, 256, 0, stream>>>(x, A, row, cnt);
    scanbucket_kernel<<<NE / 256, 256, 0, stream>>>(
        row, col, cnt, bsum, off, cur, done, done2, tick, perm);
    gather_kernel    <<<NN / 4 + BT_BLOCKS, 256, 0, stream>>>(
        ea, et, off, cnt, perm, A, Wm, Wr, Bt);
    mfma_dense_kernel<<<(NN + 63) / 64, 256, 0, stream>>>(A, Bt, bm, br, out);
}

// Round 13
// 161.660 us; speedup vs baseline: 1.9870x; 1.9870x over previous
//
#include <hip/hip_runtime.h>
#include <hip/hip_bf16.h>

#define NN 50000
#define NE 800000
#define D_NODE 64
#define D_MSG 96      // 64 + 16 + 16
#define D_K 160       // compute K: 64 (x) + 96 (0.5*agg)
#define AS 192        // A row stride in bf16 (384 B, 128B-aligned rows)
#define D_OUT 128
#define KP 168        // padded K stride for Bt (336B rows, 16B-aligned)

#define SCAN_BLOCKS 49     // ceil(12500 int4 groups / 256)
#define XCAST_BLOCKS 3125  // NN*16/256
#define BT_BLOCKS 80       // 20480 Bt elements / 256

typedef __attribute__((ext_vector_type(8))) short bf16x8;
typedef __attribute__((ext_vector_type(4))) float f32x4;

// ---------------- ws layout (all ranges disjoint / ordering-safe) ----------
// cnt : [0,        200000)
// done: [200000,   200064)    spin-barrier counter (zeroed by the memset)
// off : [200064,   400064)
// cur : [400064,   600064)    cur DEAD after bucket; Bt (43008B) rides here
// perm: [600064,   7000064)   NE * 8  (16B aligned)
// A   : [7000064,  26200064)  NN * 192 * 2   (row bases 128B-aligned)
//   A row: [x bf16 (0-63) | 0.5*msg_x (64-127) | 0.5*msg_e (128-159) | pad]
// bsum: A_OFF+128 (A row 0 cols 64..161): written by scan AFTER prep/xcast
//   (xcast touches cols 0-63 only), read before gather overwrites cols 64+.
#define CNT_OFF  0
#define DONE_OFF 200000
#define OFF_OFF  200064
#define CUR_OFF  400064
#define PERM_OFF 600064
#define A_OFF    7000064
#define BSUM_OFF (A_OFF + 128)

__device__ __forceinline__ unsigned short f2bf(float f) {
    __hip_bfloat16 h = __float2bfloat16(f);   // RNE
    union { __hip_bfloat16 h; unsigned short u; } c; c.h = h;
    return c.u;
}
__device__ __forceinline__ float bf2f(unsigned int u) {
    union { unsigned int i; float f; } c; c.i = u << 16; return c.f;
}

// ---------------------------------------------------------------------------
// Step 1 (fused): blocks [0,3125): cast x -> A cols 0..63 (bf16, aligned);
//                 blocks [3125,6250): per-row histogram.
// ---------------------------------------------------------------------------
__global__ __launch_bounds__(256) void prep_kernel(
    const float* __restrict__ x, unsigned short* __restrict__ A,
    const int* __restrict__ row, int* __restrict__ cnt)
{
    const int b = blockIdx.x;
    if (b < XCAST_BLOCKS) {
        int i = b * 256 + threadIdx.x;        // < NN*16 exactly
        int node = i >> 4, c4 = i & 15;
        float4 v = *(const float4*)(x + (size_t)node * D_NODE + c4 * 4);
        uint2 pk;
        pk.x = (unsigned)f2bf(v.x) | ((unsigned)f2bf(v.y) << 16);
        pk.y = (unsigned)f2bf(v.z) | ((unsigned)f2bf(v.w) << 16);
        *(uint2*)(A + (size_t)node * AS + c4 * 4) = pk;
    } else {
        int e = (b - XCAST_BLOCKS) * 256 + threadIdx.x;
        if (e < NE) atomicAdd(&cnt[row[e]], 1);
    }
}

// ---------------------------------------------------------------------------
// Step 2 (fused scanA+scanC): 49 blocks, device-scope spin barrier between
// the per-block-sum phase and the offset phase. (49 participants — safe;
// the r12 lesson: this pattern is fatal at O(1000) participants.)
// ---------------------------------------------------------------------------
__global__ __launch_bounds__(256) void scan_kernel(
    const int* __restrict__ cnt, int* __restrict__ bsum,
    int* __restrict__ off, int* __restrict__ cur, int* __restrict__ done)
{
    const int t = threadIdx.x, b = blockIdx.x;
    const int idx4 = b * 256 + t;
    const bool valid = (idx4 < NN / 4);

    // ---- phase A: this block's sum ----
    __shared__ int wsumA[4];
    int4 c = make_int4(0, 0, 0, 0);
    if (valid) c = ((const int4*)cnt)[idx4];
    int s = c.x + c.y + c.z + c.w;
    {
        int r = s;
        for (int d = 32; d > 0; d >>= 1) r += __shfl_down(r, d);
        if ((t & 63) == 0) wsumA[t >> 6] = r;
    }
    __syncthreads();
    if (t == 0) {
        bsum[b] = wsumA[0] + wsumA[1] + wsumA[2] + wsumA[3];
        __threadfence();                       // release bsum[b]
        atomicAdd(done, 1);
        while (__hip_atomic_load(done, __ATOMIC_ACQUIRE,
                                 __HIP_MEMORY_SCOPE_AGENT) < SCAN_BLOCKS)
            __builtin_amdgcn_s_sleep(1);
    }
    __syncthreads();                           // all threads see bsum complete

    // ---- phase C: offsets ----
    __shared__ int s_boff;
    __shared__ int wsumC[4];
    if (t < 64) {                              // wave 0: scan the 49 block sums
        int v = (t < SCAN_BLOCKS) ? bsum[t] : 0;
        int orig = v;
        for (int d = 1; d < 64; d <<= 1) {
            int u = __shfl_up(v, d);
            if (t >= d) v += u;
        }
        int excl = v - orig;
        int want = __shfl(excl, b);
        if (t == 0) s_boff = want;
    }

    const int lane = t & 63, w = t >> 6;
    int v = s;
    for (int d = 1; d < 64; d <<= 1) {
        int u = __shfl_up(v, d);
        if (lane >= d) v += u;
    }
    if (lane == 63) wsumC[w] = v;
    __syncthreads();
    int woff = 0;
    for (int i = 0; i < 4; ++i) if (i < w) woff += wsumC[i];

    if (valid) {
        int excl = (v - s) + woff + s_boff;
        int4 o;
        o.x = excl;
        o.y = o.x + c.x;
        o.z = o.y + c.y;
        o.w = o.z + c.z;
        ((int4*)off)[idx4] = o;
        ((int4*)cur)[idx4] = o;
    }
}

// ---------------------------------------------------------------------------
// Step 3: bucket edges into CSR slots; store (e, col[e]).
// ---------------------------------------------------------------------------
__global__ __launch_bounds__(256) void bucket_kernel(
    const int* __restrict__ row, const int* __restrict__ col,
    int* __restrict__ cur, int2* __restrict__ perm)
{
    int e = blockIdx.x * blockDim.x + threadIdx.x;
    if (e >= NE) return;
    int pos = atomicAdd(&cur[row[e]], 1);
    perm[pos] = make_int2(e, col[e]);
}

// ---------------------------------------------------------------------------
// Step 4: gather-aggregate (blocks [0, NN/4)), 2 edges per wave-pass,
// 8-edge main unroll. Extra blocks convert B = [Wr ; Wm] -> bf16 Bt.
// ---------------------------------------------------------------------------
__global__ __launch_bounds__(256) void gather_kernel(
    const float* __restrict__ ea,   // NE x 16
    const float* __restrict__ et,   // NE x 16
    const int*  __restrict__ off,
    const int*  __restrict__ cnt,
    const int2* __restrict__ perm,
    unsigned short* __restrict__ A,
    const float* __restrict__ Wm,   // 96 x 128
    const float* __restrict__ Wr,   // 64 x 128
    unsigned short* __restrict__ Bt)
{
    const int grp = blockIdx.x;
    if (grp >= NN / 4) {
        int idx = (grp - NN / 4) * 256 + threadIdx.x;   // [0, 20480)
        int n = idx & 127, k = idx >> 7;
        float v = (k < D_NODE) ? Wr[k * D_OUT + n] : Wm[(k - D_NODE) * D_OUT + n];
        Bt[n * KP + k] = f2bf(v);
        return;
    }

    const int node = grp * 4 + (threadIdx.x >> 6);   // NN % 4 == 0
    const int lane = threadIdx.x & 63;

    const int beg = off[node];
    const int end = beg + cnt[node];

    const int half = lane >> 5;          // 0: even edge of pair, 1: odd
    const int hl   = lane & 31;
    const float* ebase = ((lane >> 4) & 1) ? et : ea;
    const int ecol = lane & 15;

    float accx0 = 0.f, accx1 = 0.f, acce = 0.f;
    float accx0b = 0.f, accx1b = 0.f, acceb = 0.f;

#define EDGE_PAIR(q, ax0, ax1, ae)                                          \
    {                                                                       \
        int cc = half ? (q).w : (q).y;                                      \
        int ee = half ? (q).z : (q).x;                                      \
        unsigned xv = *(const unsigned*)(A + (size_t)cc * AS + hl * 2);     \
        float ev = ebase[(size_t)ee * 16 + ecol];                           \
        ax0 += bf2f(xv & 0xffffu);                                          \
        ax1 += bf2f(xv >> 16);                                              \
        ae  += ev;                                                          \
    }

    int j = beg;
    if ((j & 1) && j < end) {            // peel to even index
        int2 p = perm[j];
        if (half == 0) {
            unsigned xv = *(const unsigned*)(A + (size_t)p.y * AS + hl * 2);
            accx0 += bf2f(xv & 0xffffu);
            accx1 += bf2f(xv >> 16);
            acce  += ebase[(size_t)p.x * 16 + ecol];
        }
        ++j;
    }
    for (; j + 8 <= end; j += 8) {       // 4 pairs per iter
        int4 q0 = *(const int4*)(perm + j);
        int4 q1 = *(const int4*)(perm + j + 2);
        int4 q2 = *(const int4*)(perm + j + 4);
        int4 q3 = *(const int4*)(perm + j + 6);
        EDGE_PAIR(q0, accx0, accx1, acce)
        EDGE_PAIR(q1, accx0b, accx1b, acceb)
        EDGE_PAIR(q2, accx0, accx1, acce)
        EDGE_PAIR(q3, accx0b, accx1b, acceb)
    }
    if (j + 4 <= end) {
        int4 q0 = *(const int4*)(perm + j);
        int4 q1 = *(const int4*)(perm + j + 2);
        EDGE_PAIR(q0, accx0, accx1, acce)
        EDGE_PAIR(q1, accx0b, accx1b, acceb)
        j += 4;
    }
    if (j + 2 <= end) {
        int4 q0 = *(const int4*)(perm + j);
        EDGE_PAIR(q0, accx0, accx1, acce)
        j += 2;
    }
    if (j < end) {
        int2 p = perm[j];
        if (half == 0) {
            unsigned xv = *(const unsigned*)(A + (size_t)p.y * AS + hl * 2);
            accx0 += bf2f(xv & 0xffffu);
            accx1 += bf2f(xv >> 16);
            acce  += ebase[(size_t)p.x * 16 + ecol];
        }
    }
#undef EDGE_PAIR

    accx0 += accx0b; accx1 += accx1b; acce += acceb;
    accx0 += __shfl_xor(accx0, 32);
    accx1 += __shfl_xor(accx1, 32);
    acce  += __shfl_xor(acce, 32);

    unsigned short* dst = A + (size_t)node * AS;
    if (half == 0) {
        unsigned pk = (unsigned)f2bf(0.5f * accx0)
                    | ((unsigned)f2bf(0.5f * accx1) << 16);
        *(unsigned*)(dst + D_NODE + hl * 2) = pk;       // cols 64..127
    } else {
        dst[2 * D_NODE + hl] = f2bf(0.5f * acce);       // cols 128..159
    }
}

// ---------------------------------------------------------------------------
// Step 5: MFMA GEMM  out[50000,128] = A[:, 0:160] @ Bt^T + bias.
// No LDS, no barrier; B-fragments from L2-resident pre-converted Bt.
// ---------------------------------------------------------------------------
__global__ __launch_bounds__(256) void mfma_dense_kernel(
    const unsigned short* __restrict__ A,   // NN x AS bf16
    const unsigned short* __restrict__ Bt,  // 128 x KP bf16
    const float* __restrict__ bm,           // 128
    const float* __restrict__ br,           // 128
    float*       __restrict__ out)          // NN x 128
{
    const int l   = threadIdx.x & 63;
    const int wid = threadIdx.x >> 6;
    const int wm  = wid & 1;                   // M half (32 rows)
    const int wn  = wid >> 1;                  // N half (64 cols)
    const int lr  = l & 15;
    const int lk  = (l >> 4) << 3;             // k sub-offset 0/8/16/24

    bf16x8 bq[4][5];
#pragma unroll
    for (int nf = 0; nf < 4; ++nf) {
        int c = wn * 64 + nf * 16 + lr;
#pragma unroll
        for (int ks = 0; ks < 5; ++ks)
            bq[nf][ks] = *(const bf16x8*)(Bt + c * KP + ks * 32 + lk);
    }

    const int row0 = blockIdx.x * 64 + wm * 32;

    f32x4 acc[2][4];
#pragma unroll
    for (int mf = 0; mf < 2; ++mf)
#pragma unroll
        for (int nf = 0; nf < 4; ++nf)
            acc[mf][nf] = (f32x4){0.f, 0.f, 0.f, 0.f};

#pragma unroll
    for (int ks = 0; ks < 5; ++ks) {
#pragma unroll
        for (int mf = 0; mf < 2; ++mf) {
            int row = row0 + mf * 16 + lr;
            if (row > NN - 1) row = NN - 1;    // clamp (dup rows never stored)
            bf16x8 af = *(const bf16x8*)(A + (size_t)row * AS + ks * 32 + lk);
#pragma unroll
            for (int nf = 0; nf < 4; ++nf)
                acc[mf][nf] = __builtin_amdgcn_mfma_f32_16x16x32_bf16(
                    af, bq[nf][ks], acc[mf][nf], 0, 0, 0);
        }
    }

#pragma unroll
    for (int nf = 0; nf < 4; ++nf) {
        int c = wn * 64 + nf * 16 + lr;
        float bias = 0.5f * bm[c] + br[c];
#pragma unroll
        for (int mf = 0; mf < 2; ++mf) {
            int rbase = row0 + mf * 16 + ((l >> 4) << 2);
#pragma unroll
            for (int r = 0; r < 4; ++r) {
                int row = rbase + r;
                if (row < NN) out[(size_t)row * D_OUT + c] = acc[mf][nf][r] + bias;
            }
        }
    }
}

extern "C" void kernel_launch(void* const* d_in, const int* in_sizes, int n_in,
                              void* d_out, int out_size, void* d_ws, size_t ws_size,
                              hipStream_t stream) {
    const float* x  = (const float*)d_in[0];
    const int*   ei = (const int*)d_in[1];   // row = ei[0:NE), col = ei[NE:2NE)
    const float* ea = (const float*)d_in[2];
    const float* et = (const float*)d_in[3];
    const float* Wm = (const float*)d_in[4];
    const float* bm = (const float*)d_in[5];
    const float* Wr = (const float*)d_in[6];
    const float* br = (const float*)d_in[7];
    float* out = (float*)d_out;
    const int* row = ei;
    const int* col = ei + NE;

    char* ws = (char*)d_ws;
    int*  cnt  = (int*)(ws + CNT_OFF);
    int*  done = (int*)(ws + DONE_OFF);
    int*  off  = (int*)(ws + OFF_OFF);
    int*  cur  = (int*)(ws + CUR_OFF);
    int2* perm = (int2*)(ws + PERM_OFF);
    int*  bsum = (int*)(ws + BSUM_OFF);      // inside A row 0 (see layout note)
    unsigned short* A  = (unsigned short*)(ws + A_OFF);
    unsigned short* Bt = (unsigned short*)(ws + CUR_OFF);  // cur dead post-bucket

    hipMemsetAsync(ws, 0, 200064, stream);   // zero cnt + done
    prep_kernel  <<<2 * XCAST_BLOCKS, 256, 0, stream>>>(x, A, row, cnt);
    scan_kernel  <<<SCAN_BLOCKS, 256, 0, stream>>>(cnt, bsum, off, cur, done);
    bucket_kernel<<<(NE + 255) / 256, 256, 0, stream>>>(row, col, cur, perm);
    gather_kernel<<<NN / 4 + BT_BLOCKS, 256, 0, stream>>>(
        ea, et, off, cnt, perm, A, Wm, Wr, Bt);
    mfma_dense_kernel<<<(NN + 63) / 64, 256, 0, stream>>>(A, Bt, bm, br, out);
}